// Round 3
// baseline (481.088 us; speedup 1.0000x reference)
//
#include <hip/hip_runtime.h>
#include <math.h>

typedef unsigned short u16;
typedef __attribute__((ext_vector_type(8))) short bf16x8;   // 8 bf16 = 4 VGPRs
typedef __attribute__((ext_vector_type(4))) float f32x4;

static constexpr int kN = 10000;
static constexpr int kNpad = 10240;       // 80 * 128 rows per relation range
static constexpr int kD = 1024;
static constexpr int kR = 8;
static constexpr int kE = 80000;
static constexpr int kKz = 2 * kD;        // 2048 : [u | x]
static constexpr int kCrows = kNpad * (kR + 1);  // 92160 compact y_c rows (worst case)
static constexpr int kTilesY1 = kCrows / 128;    // 720 row tiles for GEMM1 (128-row)

#define GLB(p) ((const __attribute__((address_space(1))) unsigned int*)(const void*)(p))
#define LDSP(p) ((__attribute__((address_space(3))) unsigned int*)(p))

__device__ __forceinline__ u16 f2bf(float f) {
    union { float f; unsigned int i; } c; c.f = f;
    unsigned int u = c.i;
    return (u16)((u + 0x7FFFu + ((u >> 16) & 1u)) >> 16);   // RNE
}
__device__ __forceinline__ float bf2f(u16 u) {
    union { unsigned int i; float f; } c; c.i = ((unsigned int)u) << 16;
    return c.f;
}
__device__ __forceinline__ ushort4 f2bf4(float4 v) {
    ushort4 o; o.x = f2bf(v.x); o.y = f2bf(v.y); o.z = f2bf(v.z); o.w = f2bf(v.w);
    return o;
}

__global__ void zero16(uint4* __restrict__ p, long n16) {
    long i = (long)blockIdx.x * blockDim.x + threadIdx.x;
    long st = (long)gridDim.x * blockDim.x;
    uint4 z = make_uint4(0, 0, 0, 0);
    for (; i < n16; i += st) p[i] = z;
}

// Per edge: histogram dst (for CSR) and flag (rel, src) presence.
__global__ void mark_edges(const int* __restrict__ src, const int* __restrict__ dst,
                           const int* __restrict__ etype,
                           int* __restrict__ cntd, int* __restrict__ flag) {
    int e = blockIdx.x * blockDim.x + threadIdx.x;
    if (e < kE) {
        atomicAdd(&cntd[dst[e]], 1);
        flag[etype[e] * kN + src[e]] = 1;   // idempotent plain store
    }
}

// Single block, 1024 threads: exclusive scan of cnt[0..kN) -> rowptr[0..kN], zero cursor.
__global__ __launch_bounds__(1024) void scan_rowptr(const int* __restrict__ cnt,
                                                    int* __restrict__ rowptr,
                                                    int* __restrict__ cursor) {
    __shared__ int wsum[16];
    __shared__ int carry;
    const int tid = threadIdx.x;
    const int lane = tid & 63;
    const int w = tid >> 6;
    if (tid == 0) carry = 0;
    const int nchunk = (kN + 1024) / 1024;
    for (int ch = 0; ch < nchunk; ++ch) {
        int idx = ch * 1024 + tid;
        int v = (idx < kN) ? cnt[idx] : 0;
        int s = v;
#pragma unroll
        for (int off = 1; off < 64; off <<= 1) {
            int t = __shfl_up(s, off, 64);
            if (lane >= off) s += t;
        }
        if (lane == 63) wsum[w] = s;
        __syncthreads();
        if (w == 0 && lane < 16) {
            int t = wsum[lane];
#pragma unroll
            for (int off = 1; off < 16; off <<= 1) {
                int tt = __shfl_up(t, off, 64);
                if (lane >= off) t += tt;
            }
            wsum[lane] = t;
        }
        __syncthreads();
        int wpre = (w > 0) ? wsum[w - 1] : 0;
        int incl = s + wpre + carry;
        int excl = incl - v;
        if (idx <= kN) rowptr[idx] = excl;
        if (idx < kN) cursor[idx] = 0;
        __syncthreads();
        if (tid == 1023) carry = incl;
        __syncthreads();
    }
}

// 9 blocks x 1024 thr. Blocks 0..7: per-relation exclusive scan of flags ->
// sorted compact row list + pos table + count. Block 8: identity map for root.
__global__ __launch_bounds__(1024) void compact_scan(const int* __restrict__ flag,
                                                     int* __restrict__ row_src,
                                                     int* __restrict__ pos_tab,
                                                     int* __restrict__ relcnt9) {
    const int tid = threadIdx.x;
    if (blockIdx.x == kR) {   // root range: identity
        for (int i = tid; i < kNpad; i += 1024) row_src[i] = i;
        if (tid == 0) relcnt9[0] = kN;
        return;
    }
    const int r = blockIdx.x;
    const int base = kNpad * (r + 1);
    __shared__ int wsum[16];
    __shared__ int carry;
    const int lane = tid & 63;
    const int w = tid >> 6;
    if (tid == 0) carry = 0;
    const int nchunk = (kN + 1023) / 1024;
    for (int ch = 0; ch < nchunk; ++ch) {
        int idx = ch * 1024 + tid;
        int v = (idx < kN) ? flag[r * kN + idx] : 0;
        int s = v;
#pragma unroll
        for (int off = 1; off < 64; off <<= 1) {
            int t = __shfl_up(s, off, 64);
            if (lane >= off) s += t;
        }
        if (lane == 63) wsum[w] = s;
        __syncthreads();
        if (w == 0 && lane < 16) {
            int t = wsum[lane];
#pragma unroll
            for (int off = 1; off < 16; off <<= 1) {
                int tt = __shfl_up(t, off, 64);
                if (lane >= off) t += tt;
            }
            wsum[lane] = t;
        }
        __syncthreads();
        int wpre = (w > 0) ? wsum[w - 1] : 0;
        int incl = s + wpre + carry;
        int excl = incl - v;
        if (idx < kN && v) {
            row_src[base + excl] = idx;
            pos_tab[r * kN + idx] = base + excl;
        }
        __syncthreads();
        if (tid == 1023) carry = incl;
        __syncthreads();
    }
    if (tid == 0) relcnt9[r + 1] = carry;
}

// erec = (y_c row << 3) | rel, CSR-grouped by dst.
__global__ void fill_edges(const int* __restrict__ src, const int* __restrict__ dst,
                           const int* __restrict__ etype, const int* __restrict__ rowptr,
                           int* __restrict__ cursor, const int* __restrict__ pos_tab,
                           int* __restrict__ erec) {
    int e = blockIdx.x * blockDim.x + threadIdx.x;
    if (e < kE) {
        int d = dst[e], r = etype[e], s = src[e];
        int pos = rowptr[d] + atomicAdd(&cursor[d], 1);
        erec[pos] = (pos_tab[r * kN + s] << 3) | r;
    }
}

// x fp32 -> bf16 into ga[:,1024:2048].
__global__ void cvt_x(const float* __restrict__ x, u16* __restrict__ ga) {
    int row = blockIdx.x;
    int c = threadIdx.x << 2;
    float4 v = *reinterpret_cast<const float4*>(x + (size_t)row * kD + c);
    *reinterpret_cast<ushort4*>(ga + (size_t)row * kKz + kD + c) = f2bf4(v);
}

// S [rows][cols] fp32 -> D[n*ldD + k] = S[k, n] bf16. Batched square blocks.
__global__ void transpose_to_bf16(const float* __restrict__ S, u16* __restrict__ D,
                                  int rows, int cols, int ldD) {
    S += (size_t)blockIdx.z * rows * cols;
    D += (size_t)blockIdx.z * rows * cols;
    __shared__ float t[32][33];
    int c0 = blockIdx.x * 32, r0 = blockIdx.y * 32;
    int x = threadIdx.x, y = threadIdx.y;   // block (32,8)
#pragma unroll
    for (int i = 0; i < 32; i += 8)
        t[y + i][x] = S[(size_t)(r0 + y + i) * cols + c0 + x];
    __syncthreads();
#pragma unroll
    for (int i = 0; i < 32; i += 8)
        D[(size_t)(c0 + y + i) * ldD + r0 + x] = f2bf(t[x][y + i]);
}

// One block (256 thr) per dst row: u[d] = y_c[d] + bias + sum_e rs[rel]*y_c[pos].
// Writes u bf16 into ga[:,0:1024]. Edge loop unrolled x4: four row loads are
// issued before any accumulate -> 4x memory-level parallelism in the
// latency-bound gather.
__global__ __launch_bounds__(256) void aggregate(const u16* __restrict__ yc,
                                                 const float* __restrict__ bias,
                                                 const int* __restrict__ rowptr,
                                                 const int* __restrict__ erec,
                                                 u16* __restrict__ ga) {
    const int d = blockIdx.x;
    const int c = threadIdx.x << 2;
    const int e0 = rowptr[d], e1 = rowptr[d + 1];

    __shared__ float rs[kR];
    if (threadIdx.x == 0) {
        int cc[kR] = {0, 0, 0, 0, 0, 0, 0, 0};
        for (int e = e0; e < e1; ++e) cc[erec[e] & 7]++;
#pragma unroll
        for (int r = 0; r < kR; ++r) rs[r] = 1.0f / fmaxf((float)cc[r], 1.0f);
    }
    __syncthreads();

    ushort4 rv = *reinterpret_cast<const ushort4*>(yc + (size_t)d * kD + c);
    float4 bv = *reinterpret_cast<const float4*>(bias + c);
    float4 acc = make_float4(bf2f(rv.x) + bv.x, bf2f(rv.y) + bv.y,
                             bf2f(rv.z) + bv.z, bf2f(rv.w) + bv.w);

    int e = e0;
    for (; e + 3 < e1; e += 4) {
        int rec0 = erec[e], rec1 = erec[e + 1], rec2 = erec[e + 2], rec3 = erec[e + 3];
        ushort4 v0 = *reinterpret_cast<const ushort4*>(yc + (size_t)(rec0 >> 3) * kD + c);
        ushort4 v1 = *reinterpret_cast<const ushort4*>(yc + (size_t)(rec1 >> 3) * kD + c);
        ushort4 v2 = *reinterpret_cast<const ushort4*>(yc + (size_t)(rec2 >> 3) * kD + c);
        ushort4 v3 = *reinterpret_cast<const ushort4*>(yc + (size_t)(rec3 >> 3) * kD + c);
        float s0 = rs[rec0 & 7], s1 = rs[rec1 & 7], s2 = rs[rec2 & 7], s3 = rs[rec3 & 7];
        acc.x += s0 * bf2f(v0.x); acc.y += s0 * bf2f(v0.y);
        acc.z += s0 * bf2f(v0.z); acc.w += s0 * bf2f(v0.w);
        acc.x += s1 * bf2f(v1.x); acc.y += s1 * bf2f(v1.y);
        acc.z += s1 * bf2f(v1.z); acc.w += s1 * bf2f(v1.w);
        acc.x += s2 * bf2f(v2.x); acc.y += s2 * bf2f(v2.y);
        acc.z += s2 * bf2f(v2.z); acc.w += s2 * bf2f(v2.w);
        acc.x += s3 * bf2f(v3.x); acc.y += s3 * bf2f(v3.y);
        acc.z += s3 * bf2f(v3.z); acc.w += s3 * bf2f(v3.w);
    }
    for (; e < e1; ++e) {
        int rec = erec[e];
        float sc = rs[rec & 7];
        ushort4 v = *reinterpret_cast<const ushort4*>(yc + (size_t)(rec >> 3) * kD + c);
        acc.x += sc * bf2f(v.x); acc.y += sc * bf2f(v.y);
        acc.z += sc * bf2f(v.z); acc.w += sc * bf2f(v.w);
    }
    *reinterpret_cast<ushort4*>(ga + (size_t)d * kKz + c) = f2bf4(acc);
}

// GEMM1 (compacted): y_c[grow] = x_bf[row_src[grow]] @ W_{rel(grow)}^T.
// 128x128 tile, BK=32, 4 waves (each 64x64, operand-swapped MFMA).
// 3-STAGE PIPELINE with COUNTED vmcnt (T4): stage(t+2) issued while computing
// t; s_waitcnt vmcnt(8) waits only for tile t's 4 loads (t+1/t+2's 8 stay in
// flight across the barrier) -> ~2 phases of latency tolerance instead of 0.
// Raw s_barrier (no vmcnt(0) drain). Safety: stage(t+2) writes buf[(t-1)%3],
// whose readers all passed the done-barrier of iter t-1 before the stage is
// issued. Early-exit precedes all barriers (uniform per block).
__global__ __launch_bounds__(256, 3) void gemm_compact(
    const u16* __restrict__ xb, int ldx,
    const u16* __restrict__ Bt9,
    const int* __restrict__ row_src, const int* __restrict__ relcnt9,
    u16* __restrict__ yc)
{
    const int t0 = blockIdx.y;
    const int relidx = t0 / 80;
    const int lt = t0 - relidx * 80;
    if (lt * 128 >= relcnt9[relidx]) return;   // uniform early-exit (before barriers)

    __shared__ u16 sA[3][128 * 32];
    __shared__ u16 sB[3][128 * 32];

    const int tid = threadIdx.x;
    const int wave = tid >> 6;
    const int lane = tid & 63;

    const int row0 = t0 * 128;
    const int col0 = blockIdx.x * 128;

    const int srow = wave * 16 + (lane >> 2);   // 0..63
    const int scol = (lane & 3) * 8;            // 16B chunk

    const u16* gA0 = xb + (size_t)row_src[row0 + srow] * ldx + scol;
    const u16* gA1 = xb + (size_t)row_src[row0 + 64 + srow] * ldx + scol;
    const u16* gB0 = Bt9 + (size_t)(relidx * kD + col0 + srow) * kD + scol;
    const u16* gB1 = Bt9 + (size_t)(relidx * kD + col0 + 64 + srow) * kD + scol;

    const int lof0 = (wave * 16) * 32;
    const int lof1 = (64 + wave * 16) * 32;

    const int mq = (wave >> 1) * 64;
    const int nq = (wave & 1) * 64;
    const int fm = lane & 15;
    const int fk = (lane >> 4) * 8;

    f32x4 zf = {0.0f, 0.0f, 0.0f, 0.0f};
    f32x4 acc[4][4];
#pragma unroll
    for (int i = 0; i < 4; ++i)
#pragma unroll
        for (int j = 0; j < 4; ++j) acc[i][j] = zf;

    auto stage = [&](int s) {
        __builtin_amdgcn_global_load_lds(GLB(gA0), LDSP(sA[s] + lof0), 16, 0, 0);
        __builtin_amdgcn_global_load_lds(GLB(gA1), LDSP(sA[s] + lof1), 16, 0, 0);
        __builtin_amdgcn_global_load_lds(GLB(gB0), LDSP(sB[s] + lof0), 16, 0, 0);
        __builtin_amdgcn_global_load_lds(GLB(gB1), LDSP(sB[s] + lof1), 16, 0, 0);
        gA0 += 32; gA1 += 32; gB0 += 32; gB1 += 32;
    };

    constexpr int T = kD / 32;   // 32 K-steps
    stage(0);
    stage(1);

    int s = 0;
    for (int t = 0; t < T; ++t) {
        if (t + 2 < T) {
            stage(s == 0 ? 2 : (s - 1));          // (t+2)%3
            asm volatile("s_waitcnt vmcnt(8)" ::: "memory");
        } else if (t + 1 < T) {
            asm volatile("s_waitcnt vmcnt(4)" ::: "memory");
        } else {
            asm volatile("s_waitcnt vmcnt(0)" ::: "memory");
        }
        __builtin_amdgcn_s_barrier();             // ready: buf[s] loaded on all waves
        asm volatile("" ::: "memory");            // keep ds_reads below the barrier

        const u16* cA = sA[s];
        const u16* cB = sB[s];
        bf16x8 af[4], bfr[4];
#pragma unroll
        for (int i = 0; i < 4; ++i)
            af[i] = *reinterpret_cast<const bf16x8*>(&cA[(mq + i * 16 + fm) * 32 + fk]);
#pragma unroll
        for (int j = 0; j < 4; ++j)
            bfr[j] = *reinterpret_cast<const bf16x8*>(&cB[(nq + j * 16 + fm) * 32 + fk]);
#pragma unroll
        for (int i = 0; i < 4; ++i)
#pragma unroll
            for (int j = 0; j < 4; ++j)
                acc[i][j] = __builtin_amdgcn_mfma_f32_16x16x32_bf16(bfr[j], af[i], acc[i][j], 0, 0, 0);

        asm volatile("" ::: "memory");            // keep ds_reads above the barrier
        __builtin_amdgcn_s_barrier();             // done: all waves finished buf[s]
        s = (s == 2) ? 0 : (s + 1);
    }

    // Transposed C/D: row = mq + i*16 + fm, col = nq + j*16 + (lane>>4)*4 + reg
    const int cq = (lane >> 4) * 4;
#pragma unroll
    for (int i = 0; i < 4; ++i) {
        int row = row0 + mq + i * 16 + fm;   // y_c fully padded: no guard
#pragma unroll
        for (int j = 0; j < 4; ++j) {
            int col = col0 + nq + j * 16 + cq;
            f32x4 v = acc[i][j];
            ushort4 o;
            o.x = f2bf(v[0]); o.y = f2bf(v[1]); o.z = f2bf(v[2]); o.w = f2bf(v[3]);
            *reinterpret_cast<ushort4*>(yc + (size_t)row * kD + col) = o;
        }
    }
}

// GEMM2: 128x128 tile, BK=32, 4 waves, wave 64x64. Operand-swapped. Same
// 3-stage counted-vmcnt pipeline as GEMM1.
// z = A @ Bt^T + bias; h = tanh(u)*z + x*(1-z) -> Cf (fused combine).
// XCD-chunked bijective swizzle (640 blocks = 8 XCD x 80): each XCD owns 10
// contiguous row tiles x all 8 col tiles -> A panel reused 8x from its L2.
__global__ __launch_bounds__(256, 3) void gemm_mfma_gate(
    const u16* __restrict__ A, int lda,
    const u16* __restrict__ Bt, int ldb, int K,
    int M, const float* __restrict__ bias,
    float* __restrict__ Cf, const u16* __restrict__ uga, const float* __restrict__ xo)
{
    __shared__ u16 sA[3][128 * 32];
    __shared__ u16 sB[3][128 * 32];

    const int tid = threadIdx.x;
    const int wave = tid >> 6;
    const int lane = tid & 63;

    constexpr int GX = kD / 128;      // 8 col tiles
    constexpr int GY = kNpad / 128;   // 80 row tiles
    const int lin = blockIdx.y * GX + blockIdx.x;
    const int xcd = lin & 7;          // default XCD of this block
    const int pos = lin >> 3;         // 0..79 within this XCD
    const int ty = xcd * (GY / 8) + (pos >> 3);
    const int tx = pos & 7;

    const int row0 = ty * 128;
    const int col0 = tx * 128;

    const int srow = wave * 16 + (lane >> 2);
    const int scol = (lane & 3) * 8;

    const u16* gA0 = A + (size_t)(row0 + srow) * lda + scol;
    const u16* gA1 = A + (size_t)(row0 + 64 + srow) * lda + scol;
    const u16* gB0 = Bt + (size_t)(col0 + srow) * ldb + scol;
    const u16* gB1 = Bt + (size_t)(col0 + 64 + srow) * ldb + scol;

    const int lof0 = (wave * 16) * 32;
    const int lof1 = (64 + wave * 16) * 32;

    const int mq = (wave >> 1) * 64;
    const int nq = (wave & 1) * 64;
    const int fm = lane & 15;
    const int fk = (lane >> 4) * 8;

    f32x4 zf = {0.0f, 0.0f, 0.0f, 0.0f};
    f32x4 acc[4][4];
#pragma unroll
    for (int i = 0; i < 4; ++i)
#pragma unroll
        for (int j = 0; j < 4; ++j) acc[i][j] = zf;

    auto stage = [&](int s) {
        __builtin_amdgcn_global_load_lds(GLB(gA0), LDSP(sA[s] + lof0), 16, 0, 0);
        __builtin_amdgcn_global_load_lds(GLB(gA1), LDSP(sA[s] + lof1), 16, 0, 0);
        __builtin_amdgcn_global_load_lds(GLB(gB0), LDSP(sB[s] + lof0), 16, 0, 0);
        __builtin_amdgcn_global_load_lds(GLB(gB1), LDSP(sB[s] + lof1), 16, 0, 0);
        gA0 += 32; gA1 += 32; gB0 += 32; gB1 += 32;
    };

    const int T = K >> 5;   // 64 K-steps
    stage(0);
    stage(1);

    int s = 0;
    for (int t = 0; t < T; ++t) {
        if (t + 2 < T) {
            stage(s == 0 ? 2 : (s - 1));          // (t+2)%3
            asm volatile("s_waitcnt vmcnt(8)" ::: "memory");
        } else if (t + 1 < T) {
            asm volatile("s_waitcnt vmcnt(4)" ::: "memory");
        } else {
            asm volatile("s_waitcnt vmcnt(0)" ::: "memory");
        }
        __builtin_amdgcn_s_barrier();
        asm volatile("" ::: "memory");

        const u16* cA = sA[s];
        const u16* cB = sB[s];
        bf16x8 af[4], bfr[4];
#pragma unroll
        for (int i = 0; i < 4; ++i)
            af[i] = *reinterpret_cast<const bf16x8*>(&cA[(mq + i * 16 + fm) * 32 + fk]);
#pragma unroll
        for (int j = 0; j < 4; ++j)
            bfr[j] = *reinterpret_cast<const bf16x8*>(&cB[(nq + j * 16 + fm) * 32 + fk]);
#pragma unroll
        for (int i = 0; i < 4; ++i)
#pragma unroll
            for (int j = 0; j < 4; ++j)
                acc[i][j] = __builtin_amdgcn_mfma_f32_16x16x32_bf16(bfr[j], af[i], acc[i][j], 0, 0, 0);

        asm volatile("" ::: "memory");
        __builtin_amdgcn_s_barrier();
        s = (s == 2) ? 0 : (s + 1);
    }

    const int cq = (lane >> 4) * 4;
#pragma unroll
    for (int i = 0; i < 4; ++i) {
        int row = row0 + mq + i * 16 + fm;
        if (row >= M) continue;
#pragma unroll
        for (int j = 0; j < 4; ++j) {
            int col = col0 + nq + j * 16 + cq;
            f32x4 v = acc[i][j];
            float4 bv = *reinterpret_cast<const float4*>(bias + col);
            v[0] += bv.x; v[1] += bv.y; v[2] += bv.z; v[3] += bv.w;
            ushort4 ur = *reinterpret_cast<const ushort4*>(uga + (size_t)row * kKz + col);
            float4 xr = *reinterpret_cast<const float4*>(xo + (size_t)row * kD + col);
            float4 h;
            h.x = tanhf(bf2f(ur.x)) * v[0] + xr.x * (1.0f - v[0]);
            h.y = tanhf(bf2f(ur.y)) * v[1] + xr.y * (1.0f - v[1]);
            h.z = tanhf(bf2f(ur.z)) * v[2] + xr.z * (1.0f - v[2]);
            h.w = tanhf(bf2f(ur.w)) * v[3] + xr.w * (1.0f - v[3]);
            *reinterpret_cast<float4*>(Cf + (size_t)row * kD + col) = h;
        }
    }
}

extern "C" void kernel_launch(void* const* d_in, const int* in_sizes, int n_in,
                              void* d_out, int out_size, void* d_ws, size_t ws_size,
                              hipStream_t stream) {
    (void)in_sizes; (void)n_in; (void)out_size; (void)ws_size;

    const float* x     = (const float*)d_in[0];
    const int* eidx    = (const int*)d_in[1];
    const int* etype   = (const int*)d_in[2];
    const float* weight= (const float*)d_in[3];
    const float* root  = (const float*)d_in[4];
    const float* bias  = (const float*)d_in[5];
    const float* wgate = (const float*)d_in[6];
    const float* bgate = (const float*)d_in[7];
    float* out = (float*)d_out;

    const int* src = eidx;
    const int* dst = eidx + kE;

    // ---- workspace ----
    char* ws = (char*)d_ws;
    size_t off = 0;
    u16* yc   = (u16*)(ws + off);    off += (size_t)kCrows * kD * 2;   // 188.7 MB
    u16* ga   = (u16*)(ws + off);    off += (size_t)kNpad * kKz * 2;   //  41.9 MB
    u16* Bt9  = (u16*)(ws + off);    off += (size_t)(kR + 1) * kD * kD * 2; // 18.9 MB
    u16* wg_t = (u16*)(ws + off);    off += (size_t)kD * kKz * 2;      //   4.2 MB
    // int metadata (cntd|flag|row_src zeroed in one pass; all counts %4==0)
    int* cntd    = (int*)(ws + off); off += (size_t)kN * 4;            // 10000
    int* flag    = (int*)(ws + off); off += (size_t)kR * kN * 4;       // 80000
    int* row_src = (int*)(ws + off); off += (size_t)kCrows * 4;        // 92160
    int* pos_tab = (int*)(ws + off); off += (size_t)kR * kN * 4;
    int* rowp    = (int*)(ws + off); off += (size_t)(kN + 16) * 4;
    int* curs    = (int*)(ws + off); off += (size_t)kN * 4;
    int* erec    = (int*)(ws + off); off += (size_t)kE * 4;
    int* relcnt9 = (int*)(ws + off); off += 16 * 4;

    // zero cntd+flag+row_src in one pass (contiguous, 182160 ints)
    zero16<<<180, 256, 0, stream>>>((uint4*)cntd, (long)(kN + kR * kN + kCrows) / 4);

    mark_edges<<<(kE + 255) / 256, 256, 0, stream>>>(src, dst, etype, cntd, flag);
    scan_rowptr<<<1, 1024, 0, stream>>>(cntd, rowp, curs);
    compact_scan<<<kR + 1, 1024, 0, stream>>>(flag, row_src, pos_tab, relcnt9);
    fill_edges<<<(kE + 255) / 256, 256, 0, stream>>>(src, dst, etype, rowp, curs,
                                                     pos_tab, erec);

    // zero padding rows [kN, kNpad) of ga (GEMM2 + gathers read them unguarded)
    zero16<<<256, 256, 0, stream>>>((uint4*)(ga + (size_t)kN * kKz),
                                    (long)(kNpad - kN) * kKz * 2 / 16);

    // x -> bf16 into ga[:,1024:2048]
    cvt_x<<<kN, 256, 0, stream>>>(x, ga);

    // Bt9[n,k]: rows [0,1024) root^T; rows [1024(1+r),..) W_r^T. wg_t[n,k]=wgate[k,n].
    {
        dim3 b(32, 8);
        transpose_to_bf16<<<dim3(kD / 32, kD / 32, 1), b, 0, stream>>>(root, Bt9, kD, kD, kD);
        transpose_to_bf16<<<dim3(kD / 32, kD / 32, kR), b, 0, stream>>>(
            weight, Bt9 + (size_t)kD * kD, kD, kD, kD);
        transpose_to_bf16<<<dim3(kD / 32, kKz / 32, 1), b, 0, stream>>>(wgate, wg_t, kKz, kD, kKz);
    }

    // GEMM1 (compacted): y_c = gathered x rows @ per-relation W
    dim3 g1(kD / 128, kTilesY1);   // 8 x 720, ~1/3 active
    gemm_compact<<<g1, 256, 0, stream>>>(ga + kD, kKz, Bt9, row_src, relcnt9, yc);

    // aggregate: u -> ga[:,0:1024] (bf16)
    aggregate<<<kN, 256, 0, stream>>>(yc, bias, rowp, erec, ga);

    // GEMM2: z = ga @ wg_t + b_gate; h = tanh(u)*z + x*(1-z) -> out
    dim3 g2(kD / 128, kNpad / 128);    // 8 x 80
    gemm_mfma_gate<<<g2, 256, 0, stream>>>(ga, kKz, wg_t, kKz, kKz, kN, bgate, out, ga, x);
}

// Round 5
// 475.874 us; speedup vs baseline: 1.0110x; 1.0110x over previous
//
#include <hip/hip_runtime.h>
#include <math.h>

typedef unsigned short u16;
typedef __attribute__((ext_vector_type(8))) short bf16x8;   // 8 bf16 = 4 VGPRs
typedef __attribute__((ext_vector_type(4))) float f32x4;

static constexpr int kN = 10000;
static constexpr int kNpad = 10240;       // 80 * 128 rows per relation range
static constexpr int kD = 1024;
static constexpr int kR = 8;
static constexpr int kE = 80000;
static constexpr int kKz = 2 * kD;        // 2048 : [u | x]
static constexpr int kCrows = kNpad * (kR + 1);  // 92160 compact y_c rows (worst case)
static constexpr int kTilesY1 = kCrows / 128;    // 720 row tiles for GEMM1 (128-row)

#define GLB(p) ((const __attribute__((address_space(1))) unsigned int*)(const void*)(p))
#define LDSP(p) ((__attribute__((address_space(3))) unsigned int*)(p))

__device__ __forceinline__ u16 f2bf(float f) {
    union { float f; unsigned int i; } c; c.f = f;
    unsigned int u = c.i;
    return (u16)((u + 0x7FFFu + ((u >> 16) & 1u)) >> 16);   // RNE
}
__device__ __forceinline__ float bf2f(u16 u) {
    union { unsigned int i; float f; } c; c.i = ((unsigned int)u) << 16;
    return c.f;
}
__device__ __forceinline__ ushort4 f2bf4(float4 v) {
    ushort4 o; o.x = f2bf(v.x); o.y = f2bf(v.y); o.z = f2bf(v.z); o.w = f2bf(v.w);
    return o;
}

__global__ void zero16(uint4* __restrict__ p, long n16) {
    long i = (long)blockIdx.x * blockDim.x + threadIdx.x;
    long st = (long)gridDim.x * blockDim.x;
    uint4 z = make_uint4(0, 0, 0, 0);
    for (; i < n16; i += st) p[i] = z;
}

// Per edge: histogram dst (for CSR) and flag (rel, src) presence.
__global__ void mark_edges(const int* __restrict__ src, const int* __restrict__ dst,
                           const int* __restrict__ etype,
                           int* __restrict__ cntd, int* __restrict__ flag) {
    int e = blockIdx.x * blockDim.x + threadIdx.x;
    if (e < kE) {
        atomicAdd(&cntd[dst[e]], 1);
        flag[etype[e] * kN + src[e]] = 1;   // idempotent plain store
    }
}

// Single block, 1024 threads: exclusive scan of cnt[0..kN) -> rowptr[0..kN], zero cursor.
__global__ __launch_bounds__(1024) void scan_rowptr(const int* __restrict__ cnt,
                                                    int* __restrict__ rowptr,
                                                    int* __restrict__ cursor) {
    __shared__ int wsum[16];
    __shared__ int carry;
    const int tid = threadIdx.x;
    const int lane = tid & 63;
    const int w = tid >> 6;
    if (tid == 0) carry = 0;
    const int nchunk = (kN + 1024) / 1024;
    for (int ch = 0; ch < nchunk; ++ch) {
        int idx = ch * 1024 + tid;
        int v = (idx < kN) ? cnt[idx] : 0;
        int s = v;
#pragma unroll
        for (int off = 1; off < 64; off <<= 1) {
            int t = __shfl_up(s, off, 64);
            if (lane >= off) s += t;
        }
        if (lane == 63) wsum[w] = s;
        __syncthreads();
        if (w == 0 && lane < 16) {
            int t = wsum[lane];
#pragma unroll
            for (int off = 1; off < 16; off <<= 1) {
                int tt = __shfl_up(t, off, 64);
                if (lane >= off) t += tt;
            }
            wsum[lane] = t;
        }
        __syncthreads();
        int wpre = (w > 0) ? wsum[w - 1] : 0;
        int incl = s + wpre + carry;
        int excl = incl - v;
        if (idx <= kN) rowptr[idx] = excl;
        if (idx < kN) cursor[idx] = 0;
        __syncthreads();
        if (tid == 1023) carry = incl;
        __syncthreads();
    }
}

// 9 blocks x 1024 thr. Blocks 0..7: per-relation exclusive scan of flags ->
// sorted compact row list + pos table + count. Block 8: identity map for root.
__global__ __launch_bounds__(1024) void compact_scan(const int* __restrict__ flag,
                                                     int* __restrict__ row_src,
                                                     int* __restrict__ pos_tab,
                                                     int* __restrict__ relcnt9) {
    const int tid = threadIdx.x;
    if (blockIdx.x == kR) {   // root range: identity
        for (int i = tid; i < kNpad; i += 1024) row_src[i] = i;
        if (tid == 0) relcnt9[0] = kN;
        return;
    }
    const int r = blockIdx.x;
    const int base = kNpad * (r + 1);
    __shared__ int wsum[16];
    __shared__ int carry;
    const int lane = tid & 63;
    const int w = tid >> 6;
    if (tid == 0) carry = 0;
    const int nchunk = (kN + 1023) / 1024;
    for (int ch = 0; ch < nchunk; ++ch) {
        int idx = ch * 1024 + tid;
        int v = (idx < kN) ? flag[r * kN + idx] : 0;
        int s = v;
#pragma unroll
        for (int off = 1; off < 64; off <<= 1) {
            int t = __shfl_up(s, off, 64);
            if (lane >= off) s += t;
        }
        if (lane == 63) wsum[w] = s;
        __syncthreads();
        if (w == 0 && lane < 16) {
            int t = wsum[lane];
#pragma unroll
            for (int off = 1; off < 16; off <<= 1) {
                int tt = __shfl_up(t, off, 64);
                if (lane >= off) t += tt;
            }
            wsum[lane] = t;
        }
        __syncthreads();
        int wpre = (w > 0) ? wsum[w - 1] : 0;
        int incl = s + wpre + carry;
        int excl = incl - v;
        if (idx < kN && v) {
            row_src[base + excl] = idx;
            pos_tab[r * kN + idx] = base + excl;
        }
        __syncthreads();
        if (tid == 1023) carry = incl;
        __syncthreads();
    }
    if (tid == 0) relcnt9[r + 1] = carry;
}

// erec = (y_c row << 3) | rel, CSR-grouped by dst.
__global__ void fill_edges(const int* __restrict__ src, const int* __restrict__ dst,
                           const int* __restrict__ etype, const int* __restrict__ rowptr,
                           int* __restrict__ cursor, const int* __restrict__ pos_tab,
                           int* __restrict__ erec) {
    int e = blockIdx.x * blockDim.x + threadIdx.x;
    if (e < kE) {
        int d = dst[e], r = etype[e], s = src[e];
        int pos = rowptr[d] + atomicAdd(&cursor[d], 1);
        erec[pos] = (pos_tab[r * kN + s] << 3) | r;
    }
}

// x fp32 -> bf16 into ga[:,1024:2048].
__global__ void cvt_x(const float* __restrict__ x, u16* __restrict__ ga) {
    int row = blockIdx.x;
    int c = threadIdx.x << 2;
    float4 v = *reinterpret_cast<const float4*>(x + (size_t)row * kD + c);
    *reinterpret_cast<ushort4*>(ga + (size_t)row * kKz + kD + c) = f2bf4(v);
}

// S [rows][cols] fp32 -> D[n*ldD + k] = S[k, n] bf16. Batched square blocks.
__global__ void transpose_to_bf16(const float* __restrict__ S, u16* __restrict__ D,
                                  int rows, int cols, int ldD) {
    S += (size_t)blockIdx.z * rows * cols;
    D += (size_t)blockIdx.z * rows * cols;
    __shared__ float t[32][33];
    int c0 = blockIdx.x * 32, r0 = blockIdx.y * 32;
    int x = threadIdx.x, y = threadIdx.y;   // block (32,8)
#pragma unroll
    for (int i = 0; i < 32; i += 8)
        t[y + i][x] = S[(size_t)(r0 + y + i) * cols + c0 + x];
    __syncthreads();
#pragma unroll
    for (int i = 0; i < 32; i += 8)
        D[(size_t)(c0 + y + i) * ldD + r0 + x] = f2bf(t[x][y + i]);
}

// One block (256 thr) per dst row: u[d] = y_c[d] + bias + sum_e rs[rel]*y_c[pos].
// Writes u bf16 into ga[:,0:1024]. Edge loop unrolled x4 for MLP.
__global__ __launch_bounds__(256) void aggregate(const u16* __restrict__ yc,
                                                 const float* __restrict__ bias,
                                                 const int* __restrict__ rowptr,
                                                 const int* __restrict__ erec,
                                                 u16* __restrict__ ga) {
    const int d = blockIdx.x;
    const int c = threadIdx.x << 2;
    const int e0 = rowptr[d], e1 = rowptr[d + 1];

    __shared__ float rs[kR];
    if (threadIdx.x == 0) {
        int cc[kR] = {0, 0, 0, 0, 0, 0, 0, 0};
        for (int e = e0; e < e1; ++e) cc[erec[e] & 7]++;
#pragma unroll
        for (int r = 0; r < kR; ++r) rs[r] = 1.0f / fmaxf((float)cc[r], 1.0f);
    }
    __syncthreads();

    ushort4 rv = *reinterpret_cast<const ushort4*>(yc + (size_t)d * kD + c);
    float4 bv = *reinterpret_cast<const float4*>(bias + c);
    float4 acc = make_float4(bf2f(rv.x) + bv.x, bf2f(rv.y) + bv.y,
                             bf2f(rv.z) + bv.z, bf2f(rv.w) + bv.w);

    int e = e0;
    for (; e + 3 < e1; e += 4) {
        int rec0 = erec[e], rec1 = erec[e + 1], rec2 = erec[e + 2], rec3 = erec[e + 3];
        ushort4 v0 = *reinterpret_cast<const ushort4*>(yc + (size_t)(rec0 >> 3) * kD + c);
        ushort4 v1 = *reinterpret_cast<const ushort4*>(yc + (size_t)(rec1 >> 3) * kD + c);
        ushort4 v2 = *reinterpret_cast<const ushort4*>(yc + (size_t)(rec2 >> 3) * kD + c);
        ushort4 v3 = *reinterpret_cast<const ushort4*>(yc + (size_t)(rec3 >> 3) * kD + c);
        float s0 = rs[rec0 & 7], s1 = rs[rec1 & 7], s2 = rs[rec2 & 7], s3 = rs[rec3 & 7];
        acc.x += s0 * bf2f(v0.x); acc.y += s0 * bf2f(v0.y);
        acc.z += s0 * bf2f(v0.z); acc.w += s0 * bf2f(v0.w);
        acc.x += s1 * bf2f(v1.x); acc.y += s1 * bf2f(v1.y);
        acc.z += s1 * bf2f(v1.z); acc.w += s1 * bf2f(v1.w);
        acc.x += s2 * bf2f(v2.x); acc.y += s2 * bf2f(v2.y);
        acc.z += s2 * bf2f(v2.z); acc.w += s2 * bf2f(v2.w);
        acc.x += s3 * bf2f(v3.x); acc.y += s3 * bf2f(v3.y);
        acc.z += s3 * bf2f(v3.z); acc.w += s3 * bf2f(v3.w);
    }
    for (; e < e1; ++e) {
        int rec = erec[e];
        float sc = rs[rec & 7];
        ushort4 v = *reinterpret_cast<const ushort4*>(yc + (size_t)(rec >> 3) * kD + c);
        acc.x += sc * bf2f(v.x); acc.y += sc * bf2f(v.y);
        acc.z += sc * bf2f(v.z); acc.w += sc * bf2f(v.w);
    }
    *reinterpret_cast<ushort4*>(ga + (size_t)d * kKz + c) = f2bf4(acc);
}

// GEMM1 (compacted): y_c[grow] = x_bf[row_src[grow]] @ W_{rel(grow)}^T.
// 128x128 tile, BK=32, 4 waves, 3-stage counted-vmcnt pipeline (r3 structure,
// validated). LDS chunk swizzle (r3->r4, measuring this round): LDS rows are
// 64B (BK=32 bf16); unswizzled fragment reads (fixed 16B column over rows
// fm=0..15) put 8 lanes of each 16-lane group on the same 4 banks (8-way
// conflict, SQ_LDS_BANK_CONFLICT=1.57e7). Swizzle: 16B chunk c of row r is
// stored at physical chunk p = c ^ ((r>>1)&3). Write side stays linear
// (global_load_lds requirement): the SOURCE column per lane becomes
// (lane&3)^((srow>>1)&3) -- same 64B global region per 4-lane group, so zero
// traffic change. Read side: physical chunk = (lane>>4) ^ ((fm>>1)&3), a
// per-lane constant (mq,i*16,nq all ≡0 mod 8) -> no VALU in the loop.
// Spread: 8 bank_bases x 2 lanes = 2-way = free (m136).
__global__ __launch_bounds__(256, 3) void gemm_compact(
    const u16* __restrict__ xb, int ldx,
    const u16* __restrict__ Bt9,
    const int* __restrict__ row_src, const int* __restrict__ relcnt9,
    u16* __restrict__ yc)
{
    const int t0 = blockIdx.y;
    const int relidx = t0 / 80;
    const int lt = t0 - relidx * 80;
    if (lt * 128 >= relcnt9[relidx]) return;   // uniform early-exit (before barriers)

    __shared__ u16 sA[3][128 * 32];
    __shared__ u16 sB[3][128 * 32];

    const int tid = threadIdx.x;
    const int wave = tid >> 6;
    const int lane = tid & 63;

    const int row0 = t0 * 128;
    const int col0 = blockIdx.x * 128;

    const int srow = wave * 16 + (lane >> 2);                    // 0..63
    const int scol = (((lane & 3) ^ ((srow >> 1) & 3)) * 8);     // swizzled source chunk

    const u16* gA0 = xb + (size_t)row_src[row0 + srow] * ldx + scol;
    const u16* gA1 = xb + (size_t)row_src[row0 + 64 + srow] * ldx + scol;
    const u16* gB0 = Bt9 + (size_t)(relidx * kD + col0 + srow) * kD + scol;
    const u16* gB1 = Bt9 + (size_t)(relidx * kD + col0 + 64 + srow) * kD + scol;

    const int lof0 = (wave * 16) * 32;
    const int lof1 = (64 + wave * 16) * 32;

    const int mq = (wave >> 1) * 64;
    const int nq = (wave & 1) * 64;
    const int fm = lane & 15;
    const int fkx = (((lane >> 4) ^ ((fm >> 1) & 3))) * 8;       // swizzled read chunk

    f32x4 zf = {0.0f, 0.0f, 0.0f, 0.0f};
    f32x4 acc[4][4];
#pragma unroll
    for (int i = 0; i < 4; ++i)
#pragma unroll
        for (int j = 0; j < 4; ++j) acc[i][j] = zf;

    auto stage = [&](int s) {
        __builtin_amdgcn_global_load_lds(GLB(gA0), LDSP(sA[s] + lof0), 16, 0, 0);
        __builtin_amdgcn_global_load_lds(GLB(gA1), LDSP(sA[s] + lof1), 16, 0, 0);
        __builtin_amdgcn_global_load_lds(GLB(gB0), LDSP(sB[s] + lof0), 16, 0, 0);
        __builtin_amdgcn_global_load_lds(GLB(gB1), LDSP(sB[s] + lof1), 16, 0, 0);
        gA0 += 32; gA1 += 32; gB0 += 32; gB1 += 32;
    };

    constexpr int T = kD / 32;   // 32 K-steps
    stage(0);
    stage(1);

    int s = 0;
    for (int t = 0; t < T; ++t) {
        if (t + 2 < T) {
            stage(s == 0 ? 2 : (s - 1));          // (t+2)%3
            asm volatile("s_waitcnt vmcnt(8)" ::: "memory");
        } else if (t + 1 < T) {
            asm volatile("s_waitcnt vmcnt(4)" ::: "memory");
        } else {
            asm volatile("s_waitcnt vmcnt(0)" ::: "memory");
        }
        __builtin_amdgcn_s_barrier();             // ready: buf[s] loaded on all waves
        asm volatile("" ::: "memory");            // keep ds_reads below the barrier

        const u16* cA = sA[s];
        const u16* cB = sB[s];
        bf16x8 af[4], bfr[4];
#pragma unroll
        for (int i = 0; i < 4; ++i)
            af[i] = *reinterpret_cast<const bf16x8*>(&cA[(mq + i * 16 + fm) * 32 + fkx]);
#pragma unroll
        for (int j = 0; j < 4; ++j)
            bfr[j] = *reinterpret_cast<const bf16x8*>(&cB[(nq + j * 16 + fm) * 32 + fkx]);
#pragma unroll
        for (int i = 0; i < 4; ++i)
#pragma unroll
            for (int j = 0; j < 4; ++j)
                acc[i][j] = __builtin_amdgcn_mfma_f32_16x16x32_bf16(bfr[j], af[i], acc[i][j], 0, 0, 0);

        asm volatile("" ::: "memory");            // keep ds_reads above the barrier
        __builtin_amdgcn_s_barrier();             // done: all waves finished buf[s]
        s = (s == 2) ? 0 : (s + 1);
    }

    // Transposed C/D: row = mq + i*16 + fm, col = nq + j*16 + (lane>>4)*4 + reg
    const int cq = (lane >> 4) * 4;
#pragma unroll
    for (int i = 0; i < 4; ++i) {
        int row = row0 + mq + i * 16 + fm;   // y_c fully padded: no guard
#pragma unroll
        for (int j = 0; j < 4; ++j) {
            int col = col0 + nq + j * 16 + cq;
            f32x4 v = acc[i][j];
            ushort4 o;
            o.x = f2bf(v[0]); o.y = f2bf(v[1]); o.z = f2bf(v[2]); o.w = f2bf(v[3]);
            *reinterpret_cast<ushort4*>(yc + (size_t)row * kD + col) = o;
        }
    }
}

// GEMM2: 128x128 tile, BK=32, 4 waves, 3-stage counted-vmcnt pipeline + the
// same LDS chunk swizzle as GEMM1.
// z = A @ Bt^T + bias; h = tanh(u)*z + x*(1-z) -> Cf (fused combine).
// XCD-chunked bijective swizzle: each XCD owns 10 row tiles x 8 col tiles.
__global__ __launch_bounds__(256, 3) void gemm_mfma_gate(
    const u16* __restrict__ A, int lda,
    const u16* __restrict__ Bt, int ldb, int K,
    int M, const float* __restrict__ bias,
    float* __restrict__ Cf, const u16* __restrict__ uga, const float* __restrict__ xo)
{
    __shared__ u16 sA[3][128 * 32];
    __shared__ u16 sB[3][128 * 32];

    const int tid = threadIdx.x;
    const int wave = tid >> 6;
    const int lane = tid & 63;

    constexpr int GX = kD / 128;      // 8 col tiles
    constexpr int GY = kNpad / 128;   // 80 row tiles
    const int lin = blockIdx.y * GX + blockIdx.x;
    const int xcd = lin & 7;          // default XCD of this block
    const int pos = lin >> 3;         // 0..79 within this XCD
    const int ty = xcd * (GY / 8) + (pos >> 3);
    const int tx = pos & 7;

    const int row0 = ty * 128;
    const int col0 = tx * 128;

    const int srow = wave * 16 + (lane >> 2);
    const int scol = (((lane & 3) ^ ((srow >> 1) & 3)) * 8);     // swizzled source chunk

    const u16* gA0 = A + (size_t)(row0 + srow) * lda + scol;
    const u16* gA1 = A + (size_t)(row0 + 64 + srow) * lda + scol;
    const u16* gB0 = Bt + (size_t)(col0 + srow) * ldb + scol;
    const u16* gB1 = Bt + (size_t)(col0 + 64 + srow) * ldb + scol;

    const int lof0 = (wave * 16) * 32;
    const int lof1 = (64 + wave * 16) * 32;

    const int mq = (wave >> 1) * 64;
    const int nq = (wave & 1) * 64;
    const int fm = lane & 15;
    const int fkx = (((lane >> 4) ^ ((fm >> 1) & 3))) * 8;       // swizzled read chunk

    f32x4 zf = {0.0f, 0.0f, 0.0f, 0.0f};
    f32x4 acc[4][4];
#pragma unroll
    for (int i = 0; i < 4; ++i)
#pragma unroll
        for (int j = 0; j < 4; ++j) acc[i][j] = zf;

    auto stage = [&](int s) {
        __builtin_amdgcn_global_load_lds(GLB(gA0), LDSP(sA[s] + lof0), 16, 0, 0);
        __builtin_amdgcn_global_load_lds(GLB(gA1), LDSP(sA[s] + lof1), 16, 0, 0);
        __builtin_amdgcn_global_load_lds(GLB(gB0), LDSP(sB[s] + lof0), 16, 0, 0);
        __builtin_amdgcn_global_load_lds(GLB(gB1), LDSP(sB[s] + lof1), 16, 0, 0);
        gA0 += 32; gA1 += 32; gB0 += 32; gB1 += 32;
    };

    const int T = K >> 5;   // 64 K-steps
    stage(0);
    stage(1);

    int s = 0;
    for (int t = 0; t < T; ++t) {
        if (t + 2 < T) {
            stage(s == 0 ? 2 : (s - 1));          // (t+2)%3
            asm volatile("s_waitcnt vmcnt(8)" ::: "memory");
        } else if (t + 1 < T) {
            asm volatile("s_waitcnt vmcnt(4)" ::: "memory");
        } else {
            asm volatile("s_waitcnt vmcnt(0)" ::: "memory");
        }
        __builtin_amdgcn_s_barrier();
        asm volatile("" ::: "memory");

        const u16* cA = sA[s];
        const u16* cB = sB[s];
        bf16x8 af[4], bfr[4];
#pragma unroll
        for (int i = 0; i < 4; ++i)
            af[i] = *reinterpret_cast<const bf16x8*>(&cA[(mq + i * 16 + fm) * 32 + fkx]);
#pragma unroll
        for (int j = 0; j < 4; ++j)
            bfr[j] = *reinterpret_cast<const bf16x8*>(&cB[(nq + j * 16 + fm) * 32 + fkx]);
#pragma unroll
        for (int i = 0; i < 4; ++i)
#pragma unroll
            for (int j = 0; j < 4; ++j)
                acc[i][j] = __builtin_amdgcn_mfma_f32_16x16x32_bf16(bfr[j], af[i], acc[i][j], 0, 0, 0);

        asm volatile("" ::: "memory");
        __builtin_amdgcn_s_barrier();
        s = (s == 2) ? 0 : (s + 1);
    }

    const int cq = (lane >> 4) * 4;
#pragma unroll
    for (int i = 0; i < 4; ++i) {
        int row = row0 + mq + i * 16 + fm;
        if (row >= M) continue;
#pragma unroll
        for (int j = 0; j < 4; ++j) {
            int col = col0 + nq + j * 16 + cq;
            f32x4 v = acc[i][j];
            float4 bv = *reinterpret_cast<const float4*>(bias + col);
            v[0] += bv.x; v[1] += bv.y; v[2] += bv.z; v[3] += bv.w;
            ushort4 ur = *reinterpret_cast<const ushort4*>(uga + (size_t)row * kKz + col);
            float4 xr = *reinterpret_cast<const float4*>(xo + (size_t)row * kD + col);
            float4 h;
            h.x = tanhf(bf2f(ur.x)) * v[0] + xr.x * (1.0f - v[0]);
            h.y = tanhf(bf2f(ur.y)) * v[1] + xr.y * (1.0f - v[1]);
            h.z = tanhf(bf2f(ur.z)) * v[2] + xr.z * (1.0f - v[2]);
            h.w = tanhf(bf2f(ur.w)) * v[3] + xr.w * (1.0f - v[3]);
            *reinterpret_cast<float4*>(Cf + (size_t)row * kD + col) = h;
        }
    }
}

extern "C" void kernel_launch(void* const* d_in, const int* in_sizes, int n_in,
                              void* d_out, int out_size, void* d_ws, size_t ws_size,
                              hipStream_t stream) {
    (void)in_sizes; (void)n_in; (void)out_size; (void)ws_size;

    const float* x     = (const float*)d_in[0];
    const int* eidx    = (const int*)d_in[1];
    const int* etype   = (const int*)d_in[2];
    const float* weight= (const float*)d_in[3];
    const float* root  = (const float*)d_in[4];
    const float* bias  = (const float*)d_in[5];
    const float* wgate = (const float*)d_in[6];
    const float* bgate = (const float*)d_in[7];
    float* out = (float*)d_out;

    const int* src = eidx;
    const int* dst = eidx + kE;

    // ---- workspace ----
    char* ws = (char*)d_ws;
    size_t off = 0;
    u16* yc   = (u16*)(ws + off);    off += (size_t)kCrows * kD * 2;   // 188.7 MB
    u16* ga   = (u16*)(ws + off);    off += (size_t)kNpad * kKz * 2;   //  41.9 MB
    u16* Bt9  = (u16*)(ws + off);    off += (size_t)(kR + 1) * kD * kD * 2; // 18.9 MB
    u16* wg_t = (u16*)(ws + off);    off += (size_t)kD * kKz * 2;      //   4.2 MB
    // int metadata (cntd|flag|row_src zeroed in one pass; all counts %4==0)
    int* cntd    = (int*)(ws + off); off += (size_t)kN * 4;            // 10000
    int* flag    = (int*)(ws + off); off += (size_t)kR * kN * 4;       // 80000
    int* row_src = (int*)(ws + off); off += (size_t)kCrows * 4;        // 92160
    int* pos_tab = (int*)(ws + off); off += (size_t)kR * kN * 4;
    int* rowp    = (int*)(ws + off); off += (size_t)(kN + 16) * 4;
    int* curs    = (int*)(ws + off); off += (size_t)kN * 4;
    int* erec    = (int*)(ws + off); off += (size_t)kE * 4;
    int* relcnt9 = (int*)(ws + off); off += 16 * 4;

    // zero cntd+flag+row_src in one pass (contiguous, 182160 ints)
    zero16<<<180, 256, 0, stream>>>((uint4*)cntd, (long)(kN + kR * kN + kCrows) / 4);

    mark_edges<<<(kE + 255) / 256, 256, 0, stream>>>(src, dst, etype, cntd, flag);
    scan_rowptr<<<1, 1024, 0, stream>>>(cntd, rowp, curs);
    compact_scan<<<kR + 1, 1024, 0, stream>>>(flag, row_src, pos_tab, relcnt9);
    fill_edges<<<(kE + 255) / 256, 256, 0, stream>>>(src, dst, etype, rowp, curs,
                                                     pos_tab, erec);

    // zero padding rows [kN, kNpad) of ga (GEMM2 + gathers read them unguarded)
    zero16<<<256, 256, 0, stream>>>((uint4*)(ga + (size_t)kN * kKz),
                                    (long)(kNpad - kN) * kKz * 2 / 16);

    // x -> bf16 into ga[:,1024:2048]
    cvt_x<<<kN, 256, 0, stream>>>(x, ga);

    // Bt9[n,k]: rows [0,1024) root^T; rows [1024(1+r),..) W_r^T. wg_t[n,k]=wgate[k,n].
    {
        dim3 b(32, 8);
        transpose_to_bf16<<<dim3(kD / 32, kD / 32, 1), b, 0, stream>>>(root, Bt9, kD, kD, kD);
        transpose_to_bf16<<<dim3(kD / 32, kD / 32, kR), b, 0, stream>>>(
            weight, Bt9 + (size_t)kD * kD, kD, kD, kD);
        transpose_to_bf16<<<dim3(kD / 32, kKz / 32, 1), b, 0, stream>>>(wgate, wg_t, kKz, kD, kKz);
    }

    // GEMM1 (compacted): y_c = gathered x rows @ per-relation W
    dim3 g1(kD / 128, kTilesY1);   // 8 x 720, ~1/3 active
    gemm_compact<<<g1, 256, 0, stream>>>(ga + kD, kKz, Bt9, row_src, relcnt9, yc);

    // aggregate: u -> ga[:,0:1024] (bf16)
    aggregate<<<kN, 256, 0, stream>>>(yc, bias, rowp, erec, ga);

    // GEMM2: z = ga @ wg_t + b_gate; h = tanh(u)*z + x*(1-z) -> out
    dim3 g2(kD / 128, kNpad / 128);    // 8 x 80
    gemm_mfma_gate<<<g2, 256, 0, stream>>>(ga, kKz, wg_t, kKz, kKz, kN, bgate, out, ga, x);
}